// Round 1
// baseline (185.259 us; speedup 1.0000x reference)
//
#include <hip/hip_runtime.h>

// Problem constants (from reference)
#define VOCAB 50000
#define DIM   50
#define B_TOT 131072
#define CTX   10
#define NEG   10
#define EPS_F 1e-10f

constexpr int TPB    = 256;   // 4 waves
constexpr int BLOCKS = 2048;  // 8192 waves = 16384 half-waves; 8 sample-pairs per wave

// Half-wave (32 lanes) per sample; lane l holds float2 slot p = min(l,24):
//   d = 2p, 2p+1  -> 25 float2 = 50 floats exactly (no tail).
// Lanes 25..31 load a clamped duplicate (safe address) and are zeroed at the
// product stage so the 5-step xor-reduction over 32 lanes is correct.
__global__ __launch_bounds__(TPB) void cbow_loss(
    const int*   __restrict__ ctx_idx,   // [B, CTX]
    const int*   __restrict__ pos_idx,   // [B]
    const int*   __restrict__ neg_idx,   // [B, NEG]
    const float* __restrict__ inW,       // [VOCAB, DIM]
    const float* __restrict__ outW,      // [VOCAB, DIM]
    float*       __restrict__ partials)  // [BLOCKS]
{
    const int lane = threadIdx.x & 63;
    const int sub  = lane >> 5;          // which half-wave (0/1) -> which sample
    const int l    = lane & 31;          // lane within half-wave
    const int p    = (l < 25) ? l : 24;  // clamped float2 slot
    const bool act = (l < 25);

    const int wave_in_block = threadIdx.x >> 6;          // 0..3
    const int gwave  = blockIdx.x * (TPB / 64) + wave_in_block;
    const int nwaves = BLOCKS * (TPB / 64);

    const float2* __restrict__ inW2  = (const float2*)inW;   // row stride 25
    const float2* __restrict__ outW2 = (const float2*)outW;

    float loss_acc = 0.f;

    for (int pair = gwave; pair < B_TOT / 2; pair += nwaves) {
        const int b = 2 * pair + sub;

        // ---- context vector: mean over CTX gathered rows ----
        float cvx = 0.f, cvy = 0.f;
        #pragma unroll
        for (int j = 0; j < CTX; ++j) {
            const int idx = ctx_idx[b * CTX + j];       // uniform per half-wave
            const float2 v = inW2[idx * 25 + p];        // contiguous 200 B row
            cvx += v.x; cvy += v.y;
        }
        cvx *= (1.f / CTX);
        cvy *= (1.f / CTX);

        // ---- positive score ----
        float loss_b;
        {
            const int idx = pos_idx[b];
            const float2 v = outW2[idx * 25 + p];
            float prod = act ? (cvx * v.x + cvy * v.y) : 0.f;
            prod += __shfl_xor(prod, 1);
            prod += __shfl_xor(prod, 2);
            prod += __shfl_xor(prod, 4);
            prod += __shfl_xor(prod, 8);
            prod += __shfl_xor(prod, 16);
            // log(sigmoid(s) + eps)
            loss_b = __logf(1.f / (1.f + __expf(-prod)) + EPS_F);
        }

        // ---- negative scores ----
        #pragma unroll
        for (int k = 0; k < NEG; ++k) {
            const int idx = neg_idx[b * NEG + k];
            const float2 v = outW2[idx * 25 + p];
            float prod = act ? (cvx * v.x + cvy * v.y) : 0.f;
            prod += __shfl_xor(prod, 1);
            prod += __shfl_xor(prod, 2);
            prod += __shfl_xor(prod, 4);
            prod += __shfl_xor(prod, 8);
            prod += __shfl_xor(prod, 16);
            // log(sigmoid(-s) + eps) = log(1/(1+exp(s)) + eps)
            loss_b += __logf(1.f / (1.f + __expf(prod)) + EPS_F);
        }

        loss_acc += loss_b;   // identical across all 32 lanes of this half
    }

    // combine the two half-waves: every lane now holds (half0 + half1) sums
    loss_acc += __shfl_xor(loss_acc, 32);

    __shared__ float s_part[TPB / 64];
    if (lane == 0) s_part[wave_in_block] = loss_acc;
    __syncthreads();
    if (threadIdx.x == 0) {
        float s = 0.f;
        #pragma unroll
        for (int w = 0; w < TPB / 64; ++w) s += s_part[w];
        partials[blockIdx.x] = s;
    }
}

__global__ __launch_bounds__(256) void cbow_finalize(
    const float* __restrict__ partials, float* __restrict__ out)
{
    float s = 0.f;
    for (int i = threadIdx.x; i < BLOCKS; i += 256) s += partials[i];
    #pragma unroll
    for (int k = 32; k >= 1; k >>= 1) s += __shfl_xor(s, k);  // 64-lane reduce
    __shared__ float sm[4];
    const int w = threadIdx.x >> 6;
    if ((threadIdx.x & 63) == 0) sm[w] = s;
    __syncthreads();
    if (threadIdx.x == 0)
        out[0] = -(sm[0] + sm[1] + sm[2] + sm[3]) * (1.f / (float)B_TOT);
}

extern "C" void kernel_launch(void* const* d_in, const int* in_sizes, int n_in,
                              void* d_out, int out_size, void* d_ws, size_t ws_size,
                              hipStream_t stream) {
    const int*   ctx_idx = (const int*)  d_in[0];  // [B, CTX]
    const int*   pos_idx = (const int*)  d_in[1];  // [B]
    const int*   neg_idx = (const int*)  d_in[2];  // [B, NEG]
    const float* inW     = (const float*)d_in[3];  // [VOCAB, DIM]
    const float* outW    = (const float*)d_in[4];  // [VOCAB, DIM]
    float*       out     = (float*)d_out;
    float*       partials = (float*)d_ws;          // BLOCKS floats

    cbow_loss<<<BLOCKS, TPB, 0, stream>>>(ctx_idx, pos_idx, neg_idx, inW, outW, partials);
    cbow_finalize<<<1, 256, 0, stream>>>(partials, out);
}

// Round 2
// 174.789 us; speedup vs baseline: 1.0599x; 1.0599x over previous
//
#include <hip/hip_runtime.h>

// Problem constants (from reference)
#define VOCAB 50000
#define DIM   50
#define B_TOT 131072
#define CTX   10
#define NEG   10
#define EPS_F 1e-10f

constexpr int TPB    = 256;   // 4 waves
constexpr int BLOCKS = 2048;  // 8192 waves; 8 sample-pairs per wave (grid-stride)

// Half-wave (32 lanes) per sample; lane l holds float2 slot p = min(l,24):
// 25 float2 = 50 floats exactly. Lanes 25..31 load a clamped duplicate and
// are zeroed before the reduction.
//
// R2 restructure vs R1:
//  - ALL 21 indices loaded, then ALL 21 row-gathers issued into distinct
//    registers BEFORE any reduction (R1's VGPR=32 forced load serialization
//    -> latency-bound, VALUBusy 47%).
//  - Score packing: after each 5-step xor-reduce, score k is cndmask'd into
//    lane k; the sigmoid/log loss math runs ONCE over lanes 0..10 instead of
//    11 times over all 64 lanes (~90 fewer VALU instrs per pair-iteration).
//  - Loss accumulated per-lane; single 64-lane reduce at kernel end.
__global__ __launch_bounds__(TPB) void cbow_loss(
    const int*   __restrict__ ctx_idx,   // [B, CTX]
    const int*   __restrict__ pos_idx,   // [B]
    const int*   __restrict__ neg_idx,   // [B, NEG]
    const float* __restrict__ inW,       // [VOCAB, DIM]
    const float* __restrict__ outW,      // [VOCAB, DIM]
    float*       __restrict__ partials)  // [BLOCKS]
{
    const int lane = threadIdx.x & 63;
    const int sub  = lane >> 5;          // which half-wave -> which sample
    const int l    = lane & 31;          // lane within half-wave
    const int p    = (l < 25) ? l : 24;  // clamped float2 slot
    const bool act = (l < 25);

    const int wave_in_block = threadIdx.x >> 6;          // 0..3
    const int gwave  = blockIdx.x * (TPB / 64) + wave_in_block;
    const int nwaves = BLOCKS * (TPB / 64);

    const float2* __restrict__ inW2  = (const float2*)inW;   // row stride 25
    const float2* __restrict__ outW2 = (const float2*)outW;

    float loss_lane = 0.f;   // per-lane packed loss accumulator

    for (int pair = gwave; pair < B_TOT / 2; pair += nwaves) {
        const int b = 2 * pair + sub;

        // ---- phase 1: all indices ----
        int cidx[CTX];
        #pragma unroll
        for (int j = 0; j < CTX; ++j) cidx[j] = ctx_idx[b * CTX + j];
        const int pidx = pos_idx[b];
        int nidx[NEG];
        #pragma unroll
        for (int k = 0; k < NEG; ++k) nidx[k] = neg_idx[b * NEG + k];

        // ---- phase 2: issue ALL 21 gathers (independent, stay in flight) ----
        float2 cv_[CTX];
        #pragma unroll
        for (int j = 0; j < CTX; ++j) cv_[j] = inW2[cidx[j] * 25 + p];
        const float2 pv = outW2[pidx * 25 + p];
        float2 nv[NEG];
        #pragma unroll
        for (int k = 0; k < NEG; ++k) nv[k] = outW2[nidx[k] * 25 + p];

        // ---- phase 3: context mean ----
        float cvx = 0.f, cvy = 0.f;
        #pragma unroll
        for (int j = 0; j < CTX; ++j) { cvx += cv_[j].x; cvy += cv_[j].y; }
        cvx *= (1.f / CTX);
        cvy *= (1.f / CTX);

        // ---- phase 4: 11 scores, packed one per lane ----
        float packed = 0.f;
        {
            float prod = act ? (cvx * pv.x + cvy * pv.y) : 0.f;
            prod += __shfl_xor(prod, 1);
            prod += __shfl_xor(prod, 2);
            prod += __shfl_xor(prod, 4);
            prod += __shfl_xor(prod, 8);
            prod += __shfl_xor(prod, 16);
            packed = (l == 0) ? prod : packed;     // lane 0: pos score
        }
        #pragma unroll
        for (int k = 0; k < NEG; ++k) {
            float prod = act ? (cvx * nv[k].x + cvy * nv[k].y) : 0.f;
            prod += __shfl_xor(prod, 1);
            prod += __shfl_xor(prod, 2);
            prod += __shfl_xor(prod, 4);
            prod += __shfl_xor(prod, 8);
            prod += __shfl_xor(prod, 16);
            packed = (l == k + 1) ? prod : packed; // lane k+1: neg score k
        }

        // ---- phase 5: loss math ONCE for all 11 scores (lanes 0..10) ----
        // lane 0: log(sigmoid(+s)+eps); lanes 1..10: log(sigmoid(-s)+eps)
        const float z   = (l == 0) ? packed : -packed;
        const float sig = 1.f / (1.f + __expf(-z));
        const float c   = __logf(sig + EPS_F);
        loss_lane += (l < NEG + 1) ? c : 0.f;
    }

    // ---- single cross-lane reduce at the end ----
    loss_lane += __shfl_xor(loss_lane, 1);
    loss_lane += __shfl_xor(loss_lane, 2);
    loss_lane += __shfl_xor(loss_lane, 4);
    loss_lane += __shfl_xor(loss_lane, 8);
    loss_lane += __shfl_xor(loss_lane, 16);
    loss_lane += __shfl_xor(loss_lane, 32);

    __shared__ float s_part[TPB / 64];
    if (lane == 0) s_part[wave_in_block] = loss_lane;
    __syncthreads();
    if (threadIdx.x == 0) {
        float s = 0.f;
        #pragma unroll
        for (int w = 0; w < TPB / 64; ++w) s += s_part[w];
        partials[blockIdx.x] = s;
    }
}

__global__ __launch_bounds__(256) void cbow_finalize(
    const float* __restrict__ partials, float* __restrict__ out)
{
    float s = 0.f;
    for (int i = threadIdx.x; i < BLOCKS; i += 256) s += partials[i];
    #pragma unroll
    for (int k = 32; k >= 1; k >>= 1) s += __shfl_xor(s, k);  // 64-lane reduce
    __shared__ float sm[4];
    const int w = threadIdx.x >> 6;
    if ((threadIdx.x & 63) == 0) sm[w] = s;
    __syncthreads();
    if (threadIdx.x == 0)
        out[0] = -(sm[0] + sm[1] + sm[2] + sm[3]) * (1.f / (float)B_TOT);
}

extern "C" void kernel_launch(void* const* d_in, const int* in_sizes, int n_in,
                              void* d_out, int out_size, void* d_ws, size_t ws_size,
                              hipStream_t stream) {
    const int*   ctx_idx = (const int*)  d_in[0];  // [B, CTX]
    const int*   pos_idx = (const int*)  d_in[1];  // [B]
    const int*   neg_idx = (const int*)  d_in[2];  // [B, NEG]
    const float* inW     = (const float*)d_in[3];  // [VOCAB, DIM]
    const float* outW    = (const float*)d_in[4];  // [VOCAB, DIM]
    float*       out      = (float*)d_out;
    float*       partials = (float*)d_ws;          // BLOCKS floats

    cbow_loss<<<BLOCKS, TPB, 0, stream>>>(ctx_idx, pos_idx, neg_idx, inW, outW, partials);
    cbow_finalize<<<1, 256, 0, stream>>>(partials, out);
}

// Round 3
// 174.696 us; speedup vs baseline: 1.0605x; 1.0005x over previous
//
#include <hip/hip_runtime.h>

// Problem constants (from reference)
#define VOCAB 50000
#define DIM   50
#define B_TOT 131072
#define CTX   10
#define NEG   10
#define EPS_F 1e-10f
#define PAIRS (B_TOT / 2)

constexpr int TPB    = 256;   // 4 waves
constexpr int BLOCKS = 2048;  // 8192 waves; 8 pair-iterations per wave

// Half-wave (32 lanes) per sample; lane l holds float2 slot p = min(l,24).
//
// R3 vs R2: the R2 counters showed VGPR_Count=44 -> the compiler serialized
// the 21 gathers (<1 outstanding load/wave by Little's law; latency-bound at
// 100us with every pipe <50%). Fix:
//  - __launch_bounds__(256, 4): 4 waves/EU -> 128-VGPR budget, letting all
//    21 float2 gathers live in registers simultaneously.
//  - Explicit 2-stage software pipeline: next pair's 21 index loads are
//    issued while the current pair's row-gathers are in flight, so the
//    index->gather dependency chain costs one latency per iteration, and the
//    vmem queue stays ~21 deep.
__global__ __launch_bounds__(TPB, 4) void cbow_loss(
    const int*   __restrict__ ctx_idx,   // [B, CTX]
    const int*   __restrict__ pos_idx,   // [B]
    const int*   __restrict__ neg_idx,   // [B, NEG]
    const float* __restrict__ inW,       // [VOCAB, DIM]
    const float* __restrict__ outW,      // [VOCAB, DIM]
    float*       __restrict__ partials)  // [BLOCKS]
{
    const int lane = threadIdx.x & 63;
    const int sub  = lane >> 5;          // which half-wave -> which sample
    const int l    = lane & 31;          // lane within half-wave
    const int p    = (l < 25) ? l : 24;  // clamped float2 slot
    const bool act = (l < 25);

    const int wave_in_block = threadIdx.x >> 6;          // 0..3
    const int gwave  = blockIdx.x * (TPB / 64) + wave_in_block;
    const int nwaves = BLOCKS * (TPB / 64);

    const float2* __restrict__ inW2  = (const float2*)inW;   // row stride 25
    const float2* __restrict__ outW2 = (const float2*)outW;

    float loss_lane = 0.f;   // per-lane packed loss accumulator

    // ---- prologue: indices for the first pair ----
    int pair = gwave;
    int cidx[CTX], nidx[NEG], pidx;
    {
        const int b = 2 * pair + sub;
        #pragma unroll
        for (int j = 0; j < CTX; ++j) cidx[j] = ctx_idx[b * CTX + j];
        pidx = pos_idx[b];
        #pragma unroll
        for (int k = 0; k < NEG; ++k) nidx[k] = neg_idx[b * NEG + k];
    }

    while (pair < PAIRS) {
        // ---- issue ALL 21 row-gathers for the current pair ----
        float2 cv_[CTX], nv[NEG], pv;
        #pragma unroll
        for (int j = 0; j < CTX; ++j) cv_[j] = inW2[cidx[j] * 25 + p];
        pv = outW2[pidx * 25 + p];
        #pragma unroll
        for (int k = 0; k < NEG; ++k) nv[k] = outW2[nidx[k] * 25 + p];

        // ---- prefetch next pair's indices while gathers are in flight ----
        const int npair = pair + nwaves;
        {
            const int nb = 2 * ((npair < PAIRS) ? npair : pair) + sub; // safe clamp
            #pragma unroll
            for (int j = 0; j < CTX; ++j) cidx[j] = ctx_idx[nb * CTX + j];
            pidx = pos_idx[nb];
            #pragma unroll
            for (int k = 0; k < NEG; ++k) nidx[k] = neg_idx[nb * NEG + k];
        }

        // ---- context mean ----
        float cvx = 0.f, cvy = 0.f;
        #pragma unroll
        for (int j = 0; j < CTX; ++j) { cvx += cv_[j].x; cvy += cv_[j].y; }
        cvx *= (1.f / CTX);
        cvy *= (1.f / CTX);

        // ---- 11 scores, packed one per lane ----
        float packed = 0.f;
        {
            float prod = act ? (cvx * pv.x + cvy * pv.y) : 0.f;
            prod += __shfl_xor(prod, 1);
            prod += __shfl_xor(prod, 2);
            prod += __shfl_xor(prod, 4);
            prod += __shfl_xor(prod, 8);
            prod += __shfl_xor(prod, 16);
            packed = (l == 0) ? prod : packed;     // lane 0: pos score
        }
        #pragma unroll
        for (int k = 0; k < NEG; ++k) {
            float prod = act ? (cvx * nv[k].x + cvy * nv[k].y) : 0.f;
            prod += __shfl_xor(prod, 1);
            prod += __shfl_xor(prod, 2);
            prod += __shfl_xor(prod, 4);
            prod += __shfl_xor(prod, 8);
            prod += __shfl_xor(prod, 16);
            packed = (l == k + 1) ? prod : packed; // lane k+1: neg score k
        }

        // ---- loss math once for all 11 scores (lanes 0..10) ----
        const float z   = (l == 0) ? packed : -packed;
        const float sig = 1.f / (1.f + __expf(-z));
        const float c   = __logf(sig + EPS_F);
        loss_lane += (l < NEG + 1) ? c : 0.f;

        pair = npair;
    }

    // ---- single cross-lane reduce at the end ----
    loss_lane += __shfl_xor(loss_lane, 1);
    loss_lane += __shfl_xor(loss_lane, 2);
    loss_lane += __shfl_xor(loss_lane, 4);
    loss_lane += __shfl_xor(loss_lane, 8);
    loss_lane += __shfl_xor(loss_lane, 16);
    loss_lane += __shfl_xor(loss_lane, 32);

    __shared__ float s_part[TPB / 64];
    if (lane == 0) s_part[wave_in_block] = loss_lane;
    __syncthreads();
    if (threadIdx.x == 0) {
        float s = 0.f;
        #pragma unroll
        for (int w = 0; w < TPB / 64; ++w) s += s_part[w];
        partials[blockIdx.x] = s;
    }
}

__global__ __launch_bounds__(256) void cbow_finalize(
    const float* __restrict__ partials, float* __restrict__ out)
{
    float s = 0.f;
    for (int i = threadIdx.x; i < BLOCKS; i += 256) s += partials[i];
    #pragma unroll
    for (int k = 32; k >= 1; k >>= 1) s += __shfl_xor(s, k);  // 64-lane reduce
    __shared__ float sm[4];
    const int w = threadIdx.x >> 6;
    if ((threadIdx.x & 63) == 0) sm[w] = s;
    __syncthreads();
    if (threadIdx.x == 0)
        out[0] = -(sm[0] + sm[1] + sm[2] + sm[3]) * (1.f / (float)B_TOT);
}

extern "C" void kernel_launch(void* const* d_in, const int* in_sizes, int n_in,
                              void* d_out, int out_size, void* d_ws, size_t ws_size,
                              hipStream_t stream) {
    const int*   ctx_idx = (const int*)  d_in[0];  // [B, CTX]
    const int*   pos_idx = (const int*)  d_in[1];  // [B]
    const int*   neg_idx = (const int*)  d_in[2];  // [B, NEG]
    const float* inW     = (const float*)d_in[3];  // [VOCAB, DIM]
    const float* outW    = (const float*)d_in[4];  // [VOCAB, DIM]
    float*       out      = (float*)d_out;
    float*       partials = (float*)d_ws;          // BLOCKS floats

    cbow_loss<<<BLOCKS, TPB, 0, stream>>>(ctx_idx, pos_idx, neg_idx, inW, outW, partials);
    cbow_finalize<<<1, 256, 0, stream>>>(partials, out);
}

// Round 4
// 172.649 us; speedup vs baseline: 1.0730x; 1.0119x over previous
//
#include <hip/hip_runtime.h>

// Problem constants (from reference)
#define VOCAB 50000
#define DIM   50
#define B_TOT 131072
#define CTX   10
#define NEG   10
#define EPS_F 1e-10f
#define PAIRS (B_TOT / 2)

constexpr int TPB    = 256;   // 4 waves
constexpr int BLOCKS = 2048;  // 8192 waves; 8 pair-iterations per wave

// Half-wave (32 lanes) per sample; lane l holds float2 slot p = min(l,24).
//
// R4 vs R3: R3's VGPR_Count=40 proved the scheduler re-sank the gathers
// (max ~6 in flight -> latency-bound at 100us). Fixes:
//  1. __builtin_amdgcn_sched_barrier(0) after the 21 gathers: loads cannot
//     sink past it, compute cannot hoist above it -> all 21 results must be
//     live simultaneously (~21 outstanding vmem/wave).
//  2. Lane-parallel index fetch: ONE vmem instruction loads all 21 indices
//     for both samples (lane l = slot l per half-wave); per-gather index is
//     broadcast via __shfl (DS pipe). vmem instrs/pair-iter: 42 -> 22,
//     halving TA/addressing pressure.
__global__ __launch_bounds__(TPB, 4) void cbow_loss(
    const int*   __restrict__ ctx_idx,   // [B, CTX]
    const int*   __restrict__ pos_idx,   // [B]
    const int*   __restrict__ neg_idx,   // [B, NEG]
    const float* __restrict__ inW,       // [VOCAB, DIM]
    const float* __restrict__ outW,      // [VOCAB, DIM]
    float*       __restrict__ partials)  // [BLOCKS]
{
    const int lane = threadIdx.x & 63;
    const int sub  = lane >> 5;          // which half-wave -> which sample
    const int l    = lane & 31;          // lane within half-wave
    const int p    = (l < 25) ? l : 24;  // clamped float2 slot
    const bool act = (l < 25);

    const int wave_in_block = threadIdx.x >> 6;          // 0..3
    const int gwave  = blockIdx.x * (TPB / 64) + wave_in_block;
    const int nwaves = BLOCKS * (TPB / 64);

    const float2* __restrict__ inW2  = (const float2*)inW;   // row stride 25
    const float2* __restrict__ outW2 = (const float2*)outW;

    // per-lane index slot: l in 0..9 -> ctx[l]; l==10 -> pos; 11..20 -> neg[l-11]
    auto idx_addr = [&](int b) -> const int* {
        if (l < CTX)      return ctx_idx + b * CTX + l;
        if (l == CTX)     return pos_idx + b;
        if (l < CTX + 1 + NEG) return neg_idx + b * NEG + (l - CTX - 1);
        return pos_idx + b;  // lanes 21..31: harmless in-bounds dummy
    };

    float loss_lane = 0.f;   // per-lane packed loss accumulator

    int pair = gwave;
    int my_idx = *idx_addr(2 * pair + sub);   // prologue: first pair's indices

    while (pair < PAIRS) {
        // ---- broadcast indices + issue ALL 21 row-gathers ----
        float2 cv_[CTX], nv[NEG], pv;
        #pragma unroll
        for (int s = 0; s < CTX; ++s) {
            const int idx = __shfl(my_idx, (lane & 32) + s);
            cv_[s] = inW2[idx * 25 + p];
        }
        {
            const int idx = __shfl(my_idx, (lane & 32) + CTX);
            pv = outW2[idx * 25 + p];
        }
        #pragma unroll
        for (int k = 0; k < NEG; ++k) {
            const int idx = __shfl(my_idx, (lane & 32) + CTX + 1 + k);
            nv[k] = outW2[idx * 25 + p];
        }

        // ---- prefetch next pair's indices (1 vmem) while gathers fly ----
        const int npair = pair + nwaves;
        const int nb = 2 * ((npair < PAIRS) ? npair : pair) + sub;
        const int next_idx = *idx_addr(nb);

        // ---- fence: nothing crosses; forces all 21 gathers in flight ----
        __builtin_amdgcn_sched_barrier(0);

        // ---- context mean ----
        float cvx = 0.f, cvy = 0.f;
        #pragma unroll
        for (int j = 0; j < CTX; ++j) { cvx += cv_[j].x; cvy += cv_[j].y; }
        cvx *= (1.f / CTX);
        cvy *= (1.f / CTX);

        // ---- 11 scores, packed one per lane ----
        float packed = 0.f;
        {
            float prod = act ? (cvx * pv.x + cvy * pv.y) : 0.f;
            prod += __shfl_xor(prod, 1);
            prod += __shfl_xor(prod, 2);
            prod += __shfl_xor(prod, 4);
            prod += __shfl_xor(prod, 8);
            prod += __shfl_xor(prod, 16);
            packed = (l == 0) ? prod : packed;     // lane 0: pos score
        }
        #pragma unroll
        for (int k = 0; k < NEG; ++k) {
            float prod = act ? (cvx * nv[k].x + cvy * nv[k].y) : 0.f;
            prod += __shfl_xor(prod, 1);
            prod += __shfl_xor(prod, 2);
            prod += __shfl_xor(prod, 4);
            prod += __shfl_xor(prod, 8);
            prod += __shfl_xor(prod, 16);
            packed = (l == k + 1) ? prod : packed; // lane k+1: neg score k
        }

        // ---- loss math once for all 11 scores (lanes 0..10) ----
        const float z   = (l == 0) ? packed : -packed;
        const float sig = 1.f / (1.f + __expf(-z));
        const float c   = __logf(sig + EPS_F);
        loss_lane += (l < NEG + 1) ? c : 0.f;

        my_idx = next_idx;
        pair   = npair;
    }

    // ---- single cross-lane reduce at the end ----
    loss_lane += __shfl_xor(loss_lane, 1);
    loss_lane += __shfl_xor(loss_lane, 2);
    loss_lane += __shfl_xor(loss_lane, 4);
    loss_lane += __shfl_xor(loss_lane, 8);
    loss_lane += __shfl_xor(loss_lane, 16);
    loss_lane += __shfl_xor(loss_lane, 32);

    __shared__ float s_part[TPB / 64];
    if (lane == 0) s_part[wave_in_block] = loss_lane;
    __syncthreads();
    if (threadIdx.x == 0) {
        float s = 0.f;
        #pragma unroll
        for (int w = 0; w < TPB / 64; ++w) s += s_part[w];
        partials[blockIdx.x] = s;
    }
}

__global__ __launch_bounds__(256) void cbow_finalize(
    const float* __restrict__ partials, float* __restrict__ out)
{
    float s = 0.f;
    for (int i = threadIdx.x; i < BLOCKS; i += 256) s += partials[i];
    #pragma unroll
    for (int k = 32; k >= 1; k >>= 1) s += __shfl_xor(s, k);  // 64-lane reduce
    __shared__ float sm[4];
    const int w = threadIdx.x >> 6;
    if ((threadIdx.x & 63) == 0) sm[w] = s;
    __syncthreads();
    if (threadIdx.x == 0)
        out[0] = -(sm[0] + sm[1] + sm[2] + sm[3]) * (1.f / (float)B_TOT);
}

extern "C" void kernel_launch(void* const* d_in, const int* in_sizes, int n_in,
                              void* d_out, int out_size, void* d_ws, size_t ws_size,
                              hipStream_t stream) {
    const int*   ctx_idx = (const int*)  d_in[0];  // [B, CTX]
    const int*   pos_idx = (const int*)  d_in[1];  // [B]
    const int*   neg_idx = (const int*)  d_in[2];  // [B, NEG]
    const float* inW     = (const float*)d_in[3];  // [VOCAB, DIM]
    const float* outW    = (const float*)d_in[4];  // [VOCAB, DIM]
    float*       out      = (float*)d_out;
    float*       partials = (float*)d_ws;          // BLOCKS floats

    cbow_loss<<<BLOCKS, TPB, 0, stream>>>(ctx_idx, pos_idx, neg_idx, inW, outW, partials);
    cbow_finalize<<<1, 256, 0, stream>>>(partials, out);
}